// Round 1
// baseline (106.777 us; speedup 1.0000x reference)
//
#include <hip/hip_runtime.h>

// out[b,s,i] = w * x[b,s,i] + (1-w) * x[b,s,(i+1) % C],  C = 4096.
// Pure memory-bound two-tap circular stencil (the circulant matmul collapses).

#define C_DIM 4096
#define C_MASK 4095
#define C4_PER_ROW 1024   // float4 groups per row
#define C4_SHIFT 10       // log2(1024)

__global__ __launch_bounds__(256) void NormalizedCirculantMask2_kernel(
    const float* __restrict__ x,
    const float* __restrict__ wptr,
    float* __restrict__ out,
    int total4)
{
    const float w  = wptr[0];
    const float wc = 1.0f - w;

    int stride = gridDim.x * blockDim.x;
    for (int g = blockIdx.x * blockDim.x + threadIdx.x; g < total4; g += stride) {
        const float4 v = reinterpret_cast<const float4*>(x)[g];

        // row/col within the length-4096 circular dimension
        int row_base = (g >> C4_SHIFT) << 12;        // row * 4096
        int col0     = (g & (C4_PER_ROW - 1)) << 2;  // element index of v.x in row
        // wrap-around neighbor: element (col0 + 4) mod 4096
        float e = x[row_base + ((col0 + 4) & C_MASK)];

        float4 o;
        o.x = w * v.x + wc * v.y;
        o.y = w * v.y + wc * v.z;
        o.z = w * v.z + wc * v.w;
        o.w = w * v.w + wc * e;
        reinterpret_cast<float4*>(out)[g] = o;
    }
}

extern "C" void kernel_launch(void* const* d_in, const int* in_sizes, int n_in,
                              void* d_out, int out_size, void* d_ws, size_t ws_size,
                              hipStream_t stream)
{
    const float* x    = (const float*)d_in[0];
    const float* wptr = (const float*)d_in[1];
    float* out        = (float*)d_out;

    int total4 = out_size / 4;            // 16,777,216 float4 groups
    int block  = 256;
    int grid   = 2048;                    // 256 CUs x 8 blocks, grid-stride covers rest

    NormalizedCirculantMask2_kernel<<<grid, block, 0, stream>>>(x, wptr, out, total4);
}

// Round 2
// 95.284 us; speedup vs baseline: 1.1206x; 1.1206x over previous
//
#include <hip/hip_runtime.h>

// out[b,s,i] = w * x[b,s,i] + (1-w) * x[b,s,(i+1) % C],  C = 4096.
// Memory-bound two-tap circular stencil. Neighbor element fetched via
// intra-wave shuffle (lane l+1's v.x) instead of a strided scalar gather;
// only lane 63 and row-boundary lanes (g%1024==1023) do a masked fallback load.

typedef float f32x4 __attribute__((ext_vector_type(4)));

#define C_MASK 4095
#define C4_PER_ROW 1024
#define C4_SHIFT 10

__global__ __launch_bounds__(256) void NormalizedCirculantMask2_kernel(
    const float* __restrict__ x,
    const float* __restrict__ wptr,
    float* __restrict__ out,
    int total4)
{
    const float w  = wptr[0];
    const float wc = 1.0f - w;
    const int lane = threadIdx.x & 63;

    int stride = gridDim.x * blockDim.x;
    for (int g = blockIdx.x * blockDim.x + threadIdx.x; g < total4; g += stride) {
        f32x4 v = __builtin_nontemporal_load(reinterpret_cast<const f32x4*>(x) + g);

        // neighbor: element 4g+4 == v.x of group g+1 == next lane's v.x
        float vn = __shfl(v.x, lane + 1);   // garbage for lane 63, overridden below

        int gw = g & (C4_PER_ROW - 1);
        float e;
        if ((lane == 63) || (gw == C4_PER_ROW - 1)) {
            int row_base = (g >> C4_SHIFT) << 12;   // row * 4096
            int col0     = gw << 2;
            e = x[row_base + ((col0 + 4) & C_MASK)];
        } else {
            e = vn;
        }

        f32x4 o;
        o.x = w * v.x + wc * v.y;
        o.y = w * v.y + wc * v.z;
        o.z = w * v.z + wc * v.w;
        o.w = w * v.w + wc * e;
        __builtin_nontemporal_store(o, reinterpret_cast<f32x4*>(out) + g);
    }
}

extern "C" void kernel_launch(void* const* d_in, const int* in_sizes, int n_in,
                              void* d_out, int out_size, void* d_ws, size_t ws_size,
                              hipStream_t stream)
{
    const float* x    = (const float*)d_in[0];
    const float* wptr = (const float*)d_in[1];
    float* out        = (float*)d_out;

    int total4 = out_size / 4;            // 16,777,216 float4 groups
    int block  = 256;
    int grid   = 2048;                    // 256 CUs x 8 blocks, grid-stride

    NormalizedCirculantMask2_kernel<<<grid, block, 0, stream>>>(x, wptr, out, total4);
}